// Round 5
// baseline (855.538 us; speedup 1.0000x reference)
//
#include <hip/hip_runtime.h>

// HNM discriminative loss, MI355X — R5.
// predict (4,32,512,1024) f32, target (4,512,1024) i32 -> scalar f32.
// R5: TLP experiment. R1-R4 showed time invariant (~356us) under any ILP /
// staging restructure at 4 blocks/CU (occupancy 31%). Waves serialize on
// load->vmcnt(0)->consume chains, so throughput ∝ resident waves. This round:
// CHUNK 512, 4096 blocks, launch_bounds(256,8) -> 8 blocks/CU = 32 waves/CU.
// Epilogue atomics spread over 8 XCD-indexed ws replicas.

#define K_CLS 19
#define C_CH 32
#define HW_SHIFT 19            // H*W = 512*1024 = 2^19
#define HW_SIZE (1 << HW_SHIFT)
#define CHUNK 512              // pixels per block (2 per thread)
#define NREP 8                 // global ws replicas (XCD-spread)
#define EPSF 1e-12f
#define THEA_F 0.5f
#define TWO_DELTA 3.0f
#define MIN_PIX 20.0f

// per-replica ws float layout
#define OFF_SUMS 0             // 608 floats, [ch][cls] = ch*19 + s
#define OFF_CNT  608           // 19
#define OFF_SQ   627           // 19
#define OFF_POS  646           // 19
#define WS_FLOATS 665

__device__ __forceinline__ void atomAddF(float* p, float v) {
  unsafeAtomicAdd(p, v);       // native ds_add_f32 / global_atomic_add_f32
}

// sum across the 8 ws replicas
__device__ __forceinline__ float rsum(const float* ws, int idx) {
  float v = 0.f;
#pragma unroll
  for (int r = 0; r < NREP; ++r) v += ws[r * WS_FLOATS + idx];
  return v;
}

// ---- Pass 1: per-class counts + feature sums ------------------------------
__global__ __launch_bounds__(256, 8) void k_accum(
    const float* __restrict__ pred, const int* __restrict__ tgt,
    float* __restrict__ ws)
{
  __shared__ float s_sums[C_CH][2][20];   // half-wave replicas, 5 KB
  __shared__ float s_cnt[2][20];
  {
    float* z = &s_sums[0][0][0];
    for (int i = threadIdx.x; i < C_CH * 2 * 20; i += 256) z[i] = 0.f;
    if (threadIdx.x < 40) (&s_cnt[0][0])[threadIdx.x] = 0.f;
  }

  const int t = threadIdx.x;
  const int rep = (t >> 5) & 1;
  const size_t P0 = (size_t)blockIdx.x * CHUNK;   // 512 | 2^19: never crosses image
  const int n_idx = (int)(P0 >> HW_SHIFT);
  const int hw0 = (int)(P0 & (HW_SIZE - 1));

  const int2 ss = *reinterpret_cast<const int2*>(tgt + P0 + 2 * t);
  int s0 = ss.x, s1 = ss.y;
  const bool v0 = (unsigned)s0 < K_CLS;
  const bool v1 = (unsigned)s1 < K_CLS;
  if (!v0) s0 = 0;
  if (!v1) s1 = 0;

  __syncthreads();

  if (v0) atomAddF(&s_cnt[rep][s0], 1.f);
  if (v1) atomAddF(&s_cnt[rep][s1], 1.f);

  const float* base = pred + (((size_t)n_idx * C_CH) << HW_SHIFT) + hw0;
  for (int ch = 0; ch < C_CH; ++ch) {
    const float2 x = *reinterpret_cast<const float2*>(base + ((size_t)ch << HW_SHIFT) + 2 * t);
    if (v0) atomAddF(&s_sums[ch][rep][s0], x.x);
    if (v1) atomAddF(&s_sums[ch][rep][s1], x.y);
  }

  __syncthreads();
  float* wsr = ws + (blockIdx.x & (NREP - 1)) * WS_FLOATS;
  for (int i = t; i < C_CH * K_CLS; i += 256) {
    const int ch = i / K_CLS, k = i - ch * K_CLS;
    atomAddF(&wsr[OFF_SUMS + i], s_sums[ch][0][k] + s_sums[ch][1][k]);
  }
  if (t < K_CLS) atomAddF(&wsr[OFF_CNT + t], s_cnt[0][t] + s_cnt[1][t]);
}

// ---- Pass 2: per-pixel residuals (d^2 in registers) -> sq / pos -----------
__global__ __launch_bounds__(256, 8) void k_var(
    const float* __restrict__ pred, const int* __restrict__ tgt,
    float* __restrict__ ws)
{
  __shared__ float s_ctr[C_CH][20];       // 2.5 KB; 19 consecutive words/ch: conflict-free
  __shared__ float s_sq[2][20];
  __shared__ float s_pos[2][20];
  for (int i = threadIdx.x; i < C_CH * K_CLS; i += 256) {
    const int ch = i / K_CLS, k = i - ch * K_CLS;
    s_ctr[ch][k] = rsum(ws, OFF_SUMS + i) / fmaxf(rsum(ws, OFF_CNT + k), 1.f);
  }
  if (threadIdx.x < 40) {
    (&s_sq[0][0])[threadIdx.x] = 0.f;
    (&s_pos[0][0])[threadIdx.x] = 0.f;
  }

  const int t = threadIdx.x;
  const int rep = (t >> 5) & 1;
  const size_t P0 = (size_t)blockIdx.x * CHUNK;
  const int n_idx = (int)(P0 >> HW_SHIFT);
  const int hw0 = (int)(P0 & (HW_SIZE - 1));

  const int2 ss = *reinterpret_cast<const int2*>(tgt + P0 + 2 * t);
  int s0 = ss.x, s1 = ss.y;
  const bool v0 = (unsigned)s0 < K_CLS;
  const bool v1 = (unsigned)s1 < K_CLS;
  if (!v0) s0 = 0;
  if (!v1) s1 = 0;

  __syncthreads();

  float d0 = 0.f, d1 = 0.f;
  const float* base = pred + (((size_t)n_idx * C_CH) << HW_SHIFT) + hw0;
  for (int ch = 0; ch < C_CH; ++ch) {
    const float2 x = *reinterpret_cast<const float2*>(base + ((size_t)ch << HW_SHIFT) + 2 * t);
    const float c0 = s_ctr[ch][s0];
    const float c1 = s_ctr[ch][s1];
    const float e0 = c0 - x.x, e1 = c1 - x.y;
    d0 = fmaf(e0, e0, d0);
    d1 = fmaf(e1, e1, d1);
  }

  if (v0) {
    const float r = sqrtf(d0 + EPSF) - THEA_F;
    if (r > 0.f) { atomAddF(&s_sq[rep][s0], r * r); atomAddF(&s_pos[rep][s0], 1.f); }
  }
  if (v1) {
    const float r = sqrtf(d1 + EPSF) - THEA_F;
    if (r > 0.f) { atomAddF(&s_sq[rep][s1], r * r); atomAddF(&s_pos[rep][s1], 1.f); }
  }

  __syncthreads();
  float* wsr = ws + (blockIdx.x & (NREP - 1)) * WS_FLOATS;
  if (t < K_CLS) {
    atomAddF(&wsr[OFF_SQ + t], s_sq[0][t] + s_sq[1][t]);
    atomAddF(&wsr[OFF_POS + t], s_pos[0][t] + s_pos[1][t]);
  }
}

// ---- Finalize: loss_var + loss_dis + 0.001*loss_reg -----------------------
__global__ __launch_bounds__(384) void k_final(
    const float* __restrict__ ws, float* __restrict__ out)
{
  __shared__ float s_ctr[C_CH * K_CLS];
  __shared__ float s_valid[K_CLS];
  __shared__ float s_red[3];
  __shared__ float s_ncls;
  const int t = threadIdx.x;
  if (t < 3) s_red[t] = 0.f;
  if (t < K_CLS) s_valid[t] = (rsum(ws, OFF_CNT + t) > MIN_PIX) ? 1.f : 0.f;
  for (int i = t; i < C_CH * K_CLS; i += 384) {
    const int k = i % K_CLS;
    s_ctr[i] = rsum(ws, OFF_SUMS + i) / fmaxf(rsum(ws, OFF_CNT + k), 1.f);
  }
  __syncthreads();
  if (t == 0) {
    float n = 0.f;
    for (int k = 0; k < K_CLS; ++k) n += s_valid[k];
    s_ncls = fmaxf(n, 1.f);
  }
  if (t < K_CLS && s_valid[t] > 0.f) {
    atomAddF(&s_red[0], rsum(ws, OFF_SQ + t) / fmaxf(rsum(ws, OFF_POS + t), 1.f));
    float nn = 0.f;
#pragma unroll
    for (int ch = 0; ch < C_CH; ++ch) {
      const float cv = s_ctr[ch * K_CLS + t];
      nn = fmaf(cv, cv, nn);
    }
    atomAddF(&s_red[2], sqrtf(nn + EPSF));
  }
  if (t < K_CLS * K_CLS) {
    const int a = t / K_CLS, b = t - (t / K_CLS) * K_CLS;
    if (a != b && s_valid[a] > 0.f && s_valid[b] > 0.f) {
      float dd = 0.f;
#pragma unroll
      for (int ch = 0; ch < C_CH; ++ch) {
        const float df = s_ctr[ch * K_CLS + a] - s_ctr[ch * K_CLS + b];
        dd = fmaf(df, df, dd);
      }
      const float dist = sqrtf(dd + EPSF);
      const float d = fmaxf(TWO_DELTA - dist, 0.f);
      if (d > 0.f) atomAddF(&s_red[1], d * d);
    }
  }
  __syncthreads();
  if (t == 0) {
    const float n = s_ncls;
    out[0] = s_red[0] / n
           + s_red[1] / fmaxf(n * (n - 1.f), 1.f)
           + 0.001f * s_red[2] / n;
  }
}

extern "C" void kernel_launch(void* const* d_in, const int* in_sizes, int n_in,
                              void* d_out, int out_size, void* d_ws, size_t ws_size,
                              hipStream_t stream) {
  const float* pred = (const float*)d_in[0];
  const int*   tgt  = (const int*)d_in[1];
  float* ws  = (float*)d_ws;
  float* out = (float*)d_out;
  const int P = in_sizes[1];            // n*h*w = 2097152
  const int nBlocks = P / CHUNK;        // 4096

  hipMemsetAsync(d_ws, 0, NREP * WS_FLOATS * sizeof(float), stream);
  k_accum<<<nBlocks, 256, 0, stream>>>(pred, tgt, ws);
  k_var  <<<nBlocks, 256, 0, stream>>>(pred, tgt, ws);
  k_final<<<1, 384, 0, stream>>>(ws, out);
}